// Round 7
// baseline (239.530 us; speedup 1.0000x reference)
//
#include <hip/hip_runtime.h>
#include <math.h>

#define NORB    9
#define NFEAT   58
#define N_ATOMS 384
#define N_EDGES 6144
#define NK      4
#define ALLN    (N_ATOMS * NORB)              // 3456
#define NCPLX   ((long)NK * ALLN * ALLN)      // 47,775,744 complex elements

// Static orbpair feature -> (row, col, fac) maps (l = [0,1,2], dims [1,3,5], off [0,1,4])
__constant__ int c_ROWS[NFEAT] = {
    0,
    0,0,0,
    0,0,0,0,0,
    1,1,1,2,2,2,3,3,3,
    1,1,1,1,1,2,2,2,2,2,3,3,3,3,3,
    4,4,4,4,4,5,5,5,5,5,6,6,6,6,6,7,7,7,7,7,8,8,8,8,8
};
__constant__ int c_COLS[NFEAT] = {
    0,
    1,2,3,
    4,5,6,7,8,
    1,2,3,1,2,3,1,2,3,
    4,5,6,7,8,4,5,6,7,8,4,5,6,7,8,
    4,5,6,7,8,4,5,6,7,8,4,5,6,7,8,4,5,6,7,8,4,5,6,7,8
};
__constant__ float c_FACS[NFEAT] = {
    0.5f,
    1.f,1.f,1.f,
    1.f,1.f,1.f,1.f,1.f,
    0.5f,0.5f,0.5f,0.5f,0.5f,0.5f,0.5f,0.5f,0.5f,
    1.f,1.f,1.f,1.f,1.f,1.f,1.f,1.f,1.f,1.f,1.f,1.f,1.f,1.f,1.f,
    0.5f,0.5f,0.5f,0.5f,0.5f,0.5f,0.5f,0.5f,0.5f,0.5f,0.5f,0.5f,0.5f,
    0.5f,0.5f,0.5f,0.5f,0.5f,0.5f,0.5f,0.5f,0.5f,0.5f,0.5f,0.5f
};

// Grid-stride float4 zero fill. out_size = 95,551,488 divisible by 4.
__global__ void zero_kernel(float4* __restrict__ out, long n4) {
    long i = (long)blockIdx.x * blockDim.x + threadIdx.x;
    long stride = (long)gridDim.x * blockDim.x;
    float4 z = make_float4(0.f, 0.f, 0.f, 0.f);
    for (; i < n4; i += stride) out[i] = z;
}

// Layout: f32 planar-leading = np.stack([H.real, H.imag]) flat:
//   re at [cidx], im at [NCPLX + cidx], cidx = (k*ALLN + a)*ALLN + b

// Onsite: real, k-independent. val at (a,b) plus conj(=val) at (b,a), every k.
// Imag contributions are exactly zero -> skip im plane entirely.
__global__ void onsite_kernel(const float* __restrict__ ons, float* __restrict__ out,
                              long out_nf) {
    int t = blockIdx.x * blockDim.x + threadIdx.x;
    if (t >= N_ATOMS * NFEAT) return;
    int n = t / NFEAT;
    int f = t - n * NFEAT;
    float val = c_FACS[f] * ons[t];
    int a = n * NORB + c_ROWS[f];
    int b = n * NORB + c_COLS[f];
    #pragma unroll
    for (int k = 0; k < NK; ++k) {
        long base = (long)k * ALLN * ALLN;
        long p1 = base + (long)a * ALLN + b;
        long p2 = base + (long)b * ALLN + a;
        if (p1 < out_nf) atomicAdd(&out[p1], val);
        if (p2 < out_nf) atomicAdd(&out[p2], val);
    }
}

// Hopping: phase(k,e)*val at (a,b) and conjugate at (b,a).
__global__ void hop_kernel(const float* __restrict__ hop,
                           const float* __restrict__ kpts,
                           const int* __restrict__ eidx,
                           const int* __restrict__ shift,
                           float* __restrict__ out, long out_nf) {
    int t = blockIdx.x * blockDim.x + threadIdx.x;
    if (t >= N_EDGES * NFEAT) return;
    int e = t / NFEAT;
    int f = t - e * NFEAT;
    float val = c_FACS[f] * hop[t];
    int ai = eidx[e];              // edge_index[0][e] -> row atom
    int aj = eidx[N_EDGES + e];    // edge_index[1][e] -> col atom
    float sx = (float)shift[e * 3 + 0];
    float sy = (float)shift[e * 3 + 1];
    float sz = (float)shift[e * 3 + 2];
    int a = ai * NORB + c_ROWS[f];
    int b = aj * NORB + c_COLS[f];
    #pragma unroll
    for (int k = 0; k < NK; ++k) {
        float dot = kpts[k * 3 + 0] * sx + kpts[k * 3 + 1] * sy + kpts[k * 3 + 2] * sz;
        float ang = -2.0f * (float)M_PI * dot;
        float s, c;
        sincosf(ang, &s, &c);
        float re = c * val;
        float im = s * val;
        long base = (long)k * ALLN * ALLN;
        long p1 = base + (long)a * ALLN + b;     // re plane
        long p2 = base + (long)b * ALLN + a;
        if (p1 < out_nf)         atomicAdd(&out[p1], re);
        if (p2 < out_nf)         atomicAdd(&out[p2], re);
        long q1 = NCPLX + p1;                    // im plane
        long q2 = NCPLX + p2;
        if (q1 < out_nf)         atomicAdd(&out[q1], im);
        if (q2 < out_nf)         atomicAdd(&out[q2], -im);
    }
}

extern "C" void kernel_launch(void* const* d_in, const int* in_sizes, int n_in,
                              void* d_out, int out_size, void* d_ws, size_t ws_size,
                              hipStream_t stream) {
    const float* hop  = (const float*)d_in[0];   // [6144, 58] f32
    const float* ons  = (const float*)d_in[1];   // [384, 58]  f32
    const float* kpts = (const float*)d_in[2];   // [4, 3]     f32
    const int*  eidx  = (const int*)d_in[3];     // [2, 6144]  i32
    const int*  shift = (const int*)d_in[4];     // [6144, 3]  i32
    // d_out: f32, planar: [re (4*3456*3456)] then [im (4*3456*3456)]
    float* out = (float*)d_out;
    long out_nf = (long)out_size;

    {
        long n4 = out_nf / 4;
        zero_kernel<<<2048, 256, 0, stream>>>((float4*)out, n4);
    }
    {
        int total = N_ATOMS * NFEAT;
        onsite_kernel<<<(total + 255) / 256, 256, 0, stream>>>(ons, out, out_nf);
    }
    {
        int total = N_EDGES * NFEAT;
        hop_kernel<<<(total + 255) / 256, 256, 0, stream>>>(hop, kpts, eidx, shift, out, out_nf);
    }
}